// Round 3
// baseline (277.334 us; speedup 1.0000x reference)
//
#include <hip/hip_runtime.h>
#include <math.h>

#define IMG 512
#define NPIX (64 * 512 * 512)

// constants + accumulators (rewritten deterministically every launch)
// [0..27]  E[4][7]   exp vectors for sigma {0.5,1,2,4}
// [28..48] V[3][7]   (x^2/2s^2)*E for LoG sigmas {1,2,4}
// [49..51] invS4[3]  1/gsum^2 for gaussian sigmas {0.5,1,2}
// [52..54] invN2[3]  1/norm^2 for LoG sigmas {1,2,4}
// [60] loss accumulator, [61] target-sum accumulator
__device__ float g_c[64];

__device__ __forceinline__ float rdfl(float x) {
    return __uint_as_float(__builtin_amdgcn_readfirstlane(__float_as_uint(x)));
}

__global__ void precompute_kernel() {
    if (threadIdx.x != 0 || blockIdx.x != 0) return;
    const double step = 7.0 / 6.0;
    float x[7];
    for (int j = 0; j < 7; j++) x[j] = (float)(-4.0 + j * step);
    x[6] = 3.0f;
    const float sigs[4] = {0.5f, 1.0f, 2.0f, 4.0f};
    float E[4][7], Q[4][7];
    for (int s = 0; s < 4; s++) {
        float inv = 1.0f / (2.0f * sigs[s] * sigs[s]);
        for (int j = 0; j < 7; j++) {
            float q = x[j] * x[j] * inv;
            Q[s][j] = q;
            E[s][j] = expf(-q);
        }
    }
    for (int s = 0; s < 4; s++)
        for (int j = 0; j < 7; j++) g_c[s * 7 + j] = E[s][j];
    for (int s = 1; s < 4; s++)
        for (int j = 0; j < 7; j++) g_c[28 + (s - 1) * 7 + j] = Q[s][j] * E[s][j];
    for (int s = 0; s < 3; s++) {
        float gs = 0.f;
        for (int i = 0; i < 7; i++)
            for (int j = 0; j < 7; j++) gs += E[s][i] * E[s][j];
        g_c[49 + s] = 1.0f / (gs * gs);
    }
    for (int s = 1; s < 4; s++) {
        float n = 0.f;
        for (int i = 0; i < 7; i++)
            for (int j = 0; j < 7; j++) {
                float v = E[s][i] * E[s][j] * (1.0f - Q[s][i] - Q[s][j]);
                n += fabsf(v);
            }
        g_c[52 + (s - 1)] = 1.0f / (n * n);
    }
    g_c[60] = 0.f;
    g_c[61] = 0.f;
}

__global__ __launch_bounds__(256) void sum_target_kernel(const float4* __restrict__ t4) {
    int tid = blockIdx.x * 256 + threadIdx.x;
    float s = 0.f;
    for (int i = tid; i < NPIX / 4; i += 2048 * 256) {
        float4 v = t4[i];
        s += (v.x + v.y) + (v.z + v.w);
    }
    for (int off = 32; off > 0; off >>= 1) s += __shfl_down(s, off);
    __shared__ float ps[4];
    int lane = threadIdx.x & 63, wid = threadIdx.x >> 6;
    if (lane == 0) ps[wid] = s;
    __syncthreads();
    if (threadIdx.x == 0) atomicAdd(&g_c[61], (ps[0] + ps[1]) + (ps[2] + ps[3]));
}

__device__ __forceinline__ float dot7(const float c[7], const float* v) {
    float s = c[0] * v[0];
#pragma unroll
    for (int k = 1; k < 7; k++) s = fmaf(c[k], v[k], s);
    return s;
}

__device__ __forceinline__ void load10(const float* p, float* v) {
    const float2* p2 = (const float2*)p;
#pragma unroll
    for (int q = 0; q < 5; q++) {
        float2 t = p2[q];
        v[2 * q] = t.x;
        v[2 * q + 1] = t.y;
    }
}

// LDS layout (floats):
//  [0 .. 1519]        sd[38][40]   d = r-t, halo 3, zero-padded (lives whole kernel)
//  [1520 .. ]         phase 1-2:   sr[34][36], st[34][36]  (-inf padded, maxpool)
//                     phase 3-4:   h[7][32][42] transposed horizontal-conv buffer
#define HPITCH 42
#define HSZ (32 * HPITCH)  // 1344 per filter

__global__ __launch_bounds__(256) void main_kernel(const float* __restrict__ R,
                                                   const float* __restrict__ T) {
    __shared__ float lds[1520 + 7 * HSZ];  // 10928 floats = 43712 B
    float(*sd)[40] = (float(*)[40])lds;
    float(*sr)[36] = (float(*)[36])(lds + 1520);
    float(*st)[36] = (float(*)[36])(lds + 1520 + 1224);
    float* hb = lds + 1520;
    __shared__ float red[4];

    const int tid = threadIdx.x;  // 1-D block of 256
    const int gx0 = blockIdx.x * 32, gy0 = blockIdx.y * 32;
    const int base = blockIdx.z * (IMG * IMG);

    // uniform coefficients -> SGPRs (issued early, overlap with tile load)
    float E[4][7], V[3][7], invS4[3], invN2[3];
#pragma unroll
    for (int s = 0; s < 4; s++)
#pragma unroll
        for (int j = 0; j < 7; j++) E[s][j] = rdfl(g_c[s * 7 + j]);
#pragma unroll
    for (int s = 0; s < 3; s++)
#pragma unroll
        for (int j = 0; j < 7; j++) V[s][j] = rdfl(g_c[28 + s * 7 + j]);
#pragma unroll
    for (int s = 0; s < 3; s++) {
        invS4[s] = rdfl(g_c[49 + s]);
        invN2[s] = rdfl(g_c[52 + s]);
    }
    const float mean = rdfl(g_c[61]) * (1.0f / (float)NPIX);

    // ---- phase 1: load tile ----
    for (int idx = tid; idx < 38 * 38; idx += 256) {
        int i = idx / 38, j = idx - i * 38;
        int gy = gy0 + i - 3, gx = gx0 + j - 3;
        bool in = ((unsigned)gy < IMG) && ((unsigned)gx < IMG);
        float rv = 0.f, tv = 0.f;
        if (in) {
            int o = base + gy * IMG + gx;
            rv = R[o];
            tv = T[o];
        }
        sd[i][j] = rv - tv;
        if (i >= 2 && i < 36 && j >= 2 && j < 36) {
            sr[i - 2][j - 2] = in ? rv : -INFINITY;
            st[i - 2][j - 2] = in ? tv : -INFINITY;
        }
    }
    __syncthreads();

    const int x = tid & 31;
    const int y0 = (tid >> 5) * 4;  // 8 groups of 4 rows -> 32 rows

    float total = 0.f;

    // ---- phase 2: local terms (sobel, point, recon, maxpool) ----
    {
        float dw[6][3];
#pragma unroll
        for (int r = 0; r < 6; r++)
#pragma unroll
            for (int c = 0; c < 3; c++) dw[r][c] = sd[y0 + 2 + r][x + 2 + c];
        float rx[6], rs[6];
#pragma unroll
        for (int r = 0; r < 6; r++) {
            rx[r] = dw[r][2] - dw[r][0];
            rs[r] = dw[r][0] + 2.f * dw[r][1] + dw[r][2];
        }
        float crm[6], ctm[6], tc[6];
#pragma unroll
        for (int r = 0; r < 6; r++) {
            float a = sr[y0 + r][x], b = sr[y0 + r][x + 1], c = sr[y0 + r][x + 2];
            crm[r] = fmaxf(fmaxf(a, b), c);
            float a2 = st[y0 + r][x], b2 = st[y0 + r][x + 1], c2 = st[y0 + r][x + 2];
            ctm[r] = fmaxf(fmaxf(a2, b2), c2);
            tc[r] = b2;
        }
#pragma unroll
        for (int yy = 0; yy < 4; yy++) {
            float sx = rx[yy] + 2.f * rx[yy + 1] + rx[yy + 2];
            float sy = rs[yy + 2] - rs[yy];
            float pt = 4.f * dw[yy + 1][1] - dw[yy][1] - dw[yy + 2][1] - dw[yy + 1][0] -
                       dw[yy + 1][2];
            float d = dw[yy + 1][1];
            float w2 = (tc[yy + 1] > mean) ? 9.f : 1.f;
            float mr = fmaxf(fmaxf(crm[yy], crm[yy + 1]), crm[yy + 2]);
            float mt = fmaxf(fmaxf(ctm[yy], ctm[yy + 1]), ctm[yy + 2]);
            total += w2 * d * d + 2.f * (sx * sx + sy * sy) + 1.5f * pt * pt +
                     2.f * fabsf(mr - mt);
        }
    }
    __syncthreads();  // sr/st reads done; region becomes h

    // ---- phase 3: horizontal pass into transposed h[f][x][42] ----
    for (int pos = tid; pos < 38 * 32; pos += 256) {
        int y = pos >> 5, xx = pos & 31;
        const float* row = &sd[y][xx];
        float rv[7];
#pragma unroll
        for (int j = 0; j < 7; j++) rv[j] = row[j];
        float he0 = dot7(E[0], rv);
        float he1 = dot7(E[1], rv);
        float he2 = dot7(E[2], rv);
        float he3 = dot7(E[3], rv);
        float tm0 = he1 - dot7(V[0], rv);
        float tm1 = he2 - dot7(V[1], rv);
        float tm2 = he3 - dot7(V[2], rv);
        float* hp = hb + xx * HPITCH + y;
        hp[0 * HSZ] = he0;
        hp[1 * HSZ] = he1;
        hp[2 * HSZ] = he2;
        hp[3 * HSZ] = he3;
        hp[4 * HSZ] = tm0;
        hp[5 * HSZ] = tm1;
        hp[6 * HSZ] = tm2;
    }
    __syncthreads();

    // ---- phase 4: vertical pass (4-tall column per thread) ----
    {
        const float* colbase = hb + x * HPITCH + y0;
        float accL0[4] = {}, accL1[4] = {}, accL2[4] = {};
        float sv[4] = {};
        float v[10];

        load10(colbase + 0 * HSZ, v);
#pragma unroll
        for (int yy = 0; yy < 4; yy++) {
            float g = dot7(E[0], v + yy);
            sv[yy] = fmaf(invS4[0] * g, g, sv[yy]);
        }
        load10(colbase + 1 * HSZ, v);
#pragma unroll
        for (int yy = 0; yy < 4; yy++) {
            float g = dot7(E[1], v + yy);
            sv[yy] = fmaf(invS4[1] * g, g, sv[yy]);
            accL0[yy] -= dot7(V[0], v + yy);
        }
        load10(colbase + 2 * HSZ, v);
#pragma unroll
        for (int yy = 0; yy < 4; yy++) {
            float g = dot7(E[2], v + yy);
            sv[yy] = fmaf(invS4[2] * g, g, sv[yy]);
            accL1[yy] -= dot7(V[1], v + yy);
        }
        load10(colbase + 3 * HSZ, v);
#pragma unroll
        for (int yy = 0; yy < 4; yy++) accL2[yy] -= dot7(V[2], v + yy);
        load10(colbase + 4 * HSZ, v);
#pragma unroll
        for (int yy = 0; yy < 4; yy++) accL0[yy] += dot7(E[1], v + yy);
        load10(colbase + 5 * HSZ, v);
#pragma unroll
        for (int yy = 0; yy < 4; yy++) accL1[yy] += dot7(E[2], v + yy);
        load10(colbase + 6 * HSZ, v);
#pragma unroll
        for (int yy = 0; yy < 4; yy++) accL2[yy] += dot7(E[3], v + yy);

#pragma unroll
        for (int yy = 0; yy < 4; yy++) {
            total += sv[yy] + invN2[0] * accL0[yy] * accL0[yy] +
                     invN2[1] * accL1[yy] * accL1[yy] + invN2[2] * accL2[yy] * accL2[yy];
        }
    }

    // ---- reduction ----
    for (int off = 32; off > 0; off >>= 1) total += __shfl_down(total, off);
    int lane = tid & 63, wid = tid >> 6;
    if (lane == 0) red[wid] = total;
    __syncthreads();
    if (tid == 0) atomicAdd(&g_c[60], (red[0] + red[1]) + (red[2] + red[3]));
}

__global__ void finalize_kernel(float* __restrict__ out) {
    if (threadIdx.x == 0 && blockIdx.x == 0) out[0] = g_c[60] * (1.0f / (float)NPIX);
}

extern "C" void kernel_launch(void* const* d_in, const int* in_sizes, int n_in,
                              void* d_out, int out_size, void* d_ws, size_t ws_size,
                              hipStream_t stream) {
    const float* recon = (const float*)d_in[0];
    const float* target = (const float*)d_in[1];

    hipLaunchKernelGGL(precompute_kernel, dim3(1), dim3(64), 0, stream);
    hipLaunchKernelGGL(sum_target_kernel, dim3(2048), dim3(256), 0, stream,
                       (const float4*)target);
    dim3 grid(16, 16, 64), block(256);  // 1-D block: kernel uses flat threadIdx.x
    hipLaunchKernelGGL(main_kernel, grid, block, 0, stream, recon, target);
    hipLaunchKernelGGL(finalize_kernel, dim3(1), dim3(1), 0, stream, (float*)d_out);
}

// Round 4
// 270.482 us; speedup vs baseline: 1.0253x; 1.0253x over previous
//
#include <hip/hip_runtime.h>
#include <math.h>

#define IMG 512
#define NPIX (64 * 512 * 512)

// constants + accumulators (rewritten deterministically every launch)
// [0..27]  E[4][7]   exp vectors for sigma {0.5,1,2,4}
// [28..48] V[3][7]   (x^2/2s^2)*E for LoG sigmas {1,2,4}
// [49..51] invS4[3]  1/gsum^2 for gaussian sigmas {0.5,1,2}
// [52..54] invN2[3]  1/norm^2 for LoG sigmas {1,2,4}
// [60] loss accumulator, [61] target-sum accumulator
__device__ float g_c[64];

__device__ __forceinline__ float rdfl(float x) {
    return __uint_as_float(__builtin_amdgcn_readfirstlane(__float_as_uint(x)));
}

__global__ void precompute_kernel() {
    if (threadIdx.x != 0 || blockIdx.x != 0) return;
    const double step = 7.0 / 6.0;
    float x[7];
    for (int j = 0; j < 7; j++) x[j] = (float)(-4.0 + j * step);
    x[6] = 3.0f;
    const float sigs[4] = {0.5f, 1.0f, 2.0f, 4.0f};
    float E[4][7], Q[4][7];
    for (int s = 0; s < 4; s++) {
        float inv = 1.0f / (2.0f * sigs[s] * sigs[s]);
        for (int j = 0; j < 7; j++) {
            float q = x[j] * x[j] * inv;
            Q[s][j] = q;
            E[s][j] = expf(-q);
        }
    }
    for (int s = 0; s < 4; s++)
        for (int j = 0; j < 7; j++) g_c[s * 7 + j] = E[s][j];
    for (int s = 1; s < 4; s++)
        for (int j = 0; j < 7; j++) g_c[28 + (s - 1) * 7 + j] = Q[s][j] * E[s][j];
    for (int s = 0; s < 3; s++) {
        float gs = 0.f;
        for (int i = 0; i < 7; i++)
            for (int j = 0; j < 7; j++) gs += E[s][i] * E[s][j];
        g_c[49 + s] = 1.0f / (gs * gs);
    }
    for (int s = 1; s < 4; s++) {
        float n = 0.f;
        for (int i = 0; i < 7; i++)
            for (int j = 0; j < 7; j++) {
                float v = E[s][i] * E[s][j] * (1.0f - Q[s][i] - Q[s][j]);
                n += fabsf(v);
            }
        g_c[52 + (s - 1)] = 1.0f / (n * n);
    }
    g_c[60] = 0.f;
    g_c[61] = 0.f;
}

__global__ __launch_bounds__(256) void sum_target_kernel(const float4* __restrict__ t4) {
    int tid = blockIdx.x * 256 + threadIdx.x;
    float s = 0.f;
    for (int i = tid; i < NPIX / 4; i += 2048 * 256) {
        float4 v = t4[i];
        s += (v.x + v.y) + (v.z + v.w);
    }
    for (int off = 32; off > 0; off >>= 1) s += __shfl_down(s, off);
    __shared__ float ps[4];
    int lane = threadIdx.x & 63, wid = threadIdx.x >> 6;
    if (lane == 0) ps[wid] = s;
    __syncthreads();
    if (threadIdx.x == 0) atomicAdd(&g_c[61], (ps[0] + ps[1]) + (ps[2] + ps[3]));
}

__device__ __forceinline__ float dot7(const float c[7], const float* v) {
    float s = c[0] * v[0];
#pragma unroll
    for (int k = 1; k < 7; k++) s = fmaf(c[k], v[k], s);
    return s;
}

__device__ __forceinline__ void load10(const float* p, float* v) {
    const float2* p2 = (const float2*)p;
#pragma unroll
    for (int q = 0; q < 5; q++) {
        float2 t = p2[q];
        v[2 * q] = t.x;
        v[2 * q + 1] = t.y;
    }
}

// LDS layout (floats):
//  [0 .. 1519]        sd[38][40]  d = r-t; col jj = gx-(gx0-4); valid data jj in [1,39)
//  [1520 .. ]         phase 1-2:  sr[34][36], st[34][36]  (-inf padded, maxpool)
//                     phase 3-4:  h[7][32][38] transposed horizontal-conv buffer
#define HPITCH 38
#define HSZ (32 * HPITCH)  // 1216 per filter; 7*1216 = 8512

__global__ __launch_bounds__(256) void main_kernel(const float* __restrict__ R,
                                                   const float* __restrict__ T) {
    __shared__ float lds[1520 + 7 * HSZ];  // 10032 floats = 40128 B
    float(*sd)[40] = (float(*)[40])lds;
    float(*sr)[36] = (float(*)[36])(lds + 1520);
    float(*st)[36] = (float(*)[36])(lds + 1520 + 1224);
    float* hb = lds + 1520;
    __shared__ float red[4];

    const int tid = threadIdx.x;  // 1-D block of 256
    const int gx0 = blockIdx.x * 32, gy0 = blockIdx.y * 32;
    const int base = blockIdx.z * (IMG * IMG);

    // uniform coefficients -> SGPRs (issued early, overlap with tile load)
    float E[4][7], V[3][7], invS4[3], invN2[3];
#pragma unroll
    for (int s = 0; s < 4; s++)
#pragma unroll
        for (int j = 0; j < 7; j++) E[s][j] = rdfl(g_c[s * 7 + j]);
#pragma unroll
    for (int s = 0; s < 3; s++)
#pragma unroll
        for (int j = 0; j < 7; j++) V[s][j] = rdfl(g_c[28 + s * 7 + j]);
#pragma unroll
    for (int s = 0; s < 3; s++) {
        invS4[s] = rdfl(g_c[49 + s]);
        invN2[s] = rdfl(g_c[52 + s]);
    }
    const float mean = rdfl(g_c[61]) * (1.0f / (float)NPIX);

    // ---- phase 1: load tile, float4 quads, all loads issued before LDS writes ----
    // 380 quads per array: quad q -> row i = q/10, quad-col c = q%10,
    // covering gx = gx0-4+4c+e, gy = gy0+i-3.
    {
        const int q0 = tid, q1 = tid + 256;
        const bool has1 = (q1 < 380);
        const int i0 = q0 / 10, c0 = q0 - 10 * i0;
        const int i1 = q1 / 10, c1 = q1 - 10 * i1;
        const int gy_0 = gy0 + i0 - 3, gxb0 = gx0 - 4 + 4 * c0;
        const int gy_1 = gy0 + i1 - 3, gxb1 = gx0 - 4 + 4 * c1;
        const int ay0 = min(max(gy_0, 0), IMG - 1), ax0 = min(max(gxb0, 0), IMG - 4);
        const int ay1 = min(max(gy_1, 0), IMG - 1), ax1 = min(max(gxb1, 0), IMG - 4);
        const long o0 = (long)base + ay0 * IMG + ax0;
        const long o1 = (long)base + ay1 * IMG + ax1;

        float4 r0 = *(const float4*)(R + o0);
        float4 t0 = *(const float4*)(T + o0);
        float4 r1 = make_float4(0.f, 0.f, 0.f, 0.f), t1 = r1;
        if (has1) {
            r1 = *(const float4*)(R + o1);
            t1 = *(const float4*)(T + o1);
        }

        // process quad 0
        {
            float rv[4] = {r0.x, r0.y, r0.z, r0.w};
            float tv[4] = {t0.x, t0.y, t0.z, t0.w};
            const bool vy = ((unsigned)gy_0 < IMG);
            float dq[4];
            bool vmask[4];
#pragma unroll
            for (int e = 0; e < 4; e++) {
                bool v = vy && ((unsigned)(gxb0 + e) < IMG);
                vmask[e] = v;
                dq[e] = v ? (rv[e] - tv[e]) : 0.f;
            }
            *(float4*)&sd[i0][4 * c0] = make_float4(dq[0], dq[1], dq[2], dq[3]);
            if (i0 >= 2 && i0 < 36) {
#pragma unroll
                for (int e = 0; e < 4; e++) {
                    int jr = 4 * c0 + e - 3;
                    if ((unsigned)jr < 34u) {
                        sr[i0 - 2][jr] = vmask[e] ? rv[e] : -INFINITY;
                        st[i0 - 2][jr] = vmask[e] ? tv[e] : -INFINITY;
                    }
                }
            }
        }
        // process quad 1
        if (has1) {
            float rv[4] = {r1.x, r1.y, r1.z, r1.w};
            float tv[4] = {t1.x, t1.y, t1.z, t1.w};
            const bool vy = ((unsigned)gy_1 < IMG);
            float dq[4];
            bool vmask[4];
#pragma unroll
            for (int e = 0; e < 4; e++) {
                bool v = vy && ((unsigned)(gxb1 + e) < IMG);
                vmask[e] = v;
                dq[e] = v ? (rv[e] - tv[e]) : 0.f;
            }
            *(float4*)&sd[i1][4 * c1] = make_float4(dq[0], dq[1], dq[2], dq[3]);
            if (i1 >= 2 && i1 < 36) {
#pragma unroll
                for (int e = 0; e < 4; e++) {
                    int jr = 4 * c1 + e - 3;
                    if ((unsigned)jr < 34u) {
                        sr[i1 - 2][jr] = vmask[e] ? rv[e] : -INFINITY;
                        st[i1 - 2][jr] = vmask[e] ? tv[e] : -INFINITY;
                    }
                }
            }
        }
    }
    __syncthreads();

    const int x = tid & 31;
    const int y0 = (tid >> 5) * 4;  // 8 groups of 4 rows -> 32 rows

    float total = 0.f;

    // ---- phase 2: local terms (sobel, point, recon, maxpool) ----
    // sd col indices shifted +1 vs previous rounds (jj = old_j + 1)
    {
        float dw[6][3];
#pragma unroll
        for (int r = 0; r < 6; r++)
#pragma unroll
            for (int c = 0; c < 3; c++) dw[r][c] = sd[y0 + 2 + r][x + 3 + c];
        float rx[6], rs[6];
#pragma unroll
        for (int r = 0; r < 6; r++) {
            rx[r] = dw[r][2] - dw[r][0];
            rs[r] = dw[r][0] + 2.f * dw[r][1] + dw[r][2];
        }
        float crm[6], ctm[6], tc[6];
#pragma unroll
        for (int r = 0; r < 6; r++) {
            float a = sr[y0 + r][x], b = sr[y0 + r][x + 1], c = sr[y0 + r][x + 2];
            crm[r] = fmaxf(fmaxf(a, b), c);
            float a2 = st[y0 + r][x], b2 = st[y0 + r][x + 1], c2 = st[y0 + r][x + 2];
            ctm[r] = fmaxf(fmaxf(a2, b2), c2);
            tc[r] = b2;
        }
#pragma unroll
        for (int yy = 0; yy < 4; yy++) {
            float sx = rx[yy] + 2.f * rx[yy + 1] + rx[yy + 2];
            float sy = rs[yy + 2] - rs[yy];
            float pt = 4.f * dw[yy + 1][1] - dw[yy][1] - dw[yy + 2][1] - dw[yy + 1][0] -
                       dw[yy + 1][2];
            float d = dw[yy + 1][1];
            float w2 = (tc[yy + 1] > mean) ? 9.f : 1.f;
            float mr = fmaxf(fmaxf(crm[yy], crm[yy + 1]), crm[yy + 2]);
            float mt = fmaxf(fmaxf(ctm[yy], ctm[yy + 1]), ctm[yy + 2]);
            total += w2 * d * d + 2.f * (sx * sx + sy * sy) + 1.5f * pt * pt +
                     2.f * fabsf(mr - mt);
        }
    }
    __syncthreads();  // sr/st reads done; region becomes h

    // ---- phase 3: horizontal pass into transposed h[f][32][38] ----
    for (int pos = tid; pos < 38 * 32; pos += 256) {
        int y = pos >> 5, xx = pos & 31;
        const float* row = &sd[y][xx + 1];
        float rv[7];
#pragma unroll
        for (int j = 0; j < 7; j++) rv[j] = row[j];
        float he0 = dot7(E[0], rv);
        float he1 = dot7(E[1], rv);
        float he2 = dot7(E[2], rv);
        float he3 = dot7(E[3], rv);
        float tm0 = he1 - dot7(V[0], rv);
        float tm1 = he2 - dot7(V[1], rv);
        float tm2 = he3 - dot7(V[2], rv);
        float* hp = hb + xx * HPITCH + y;
        hp[0 * HSZ] = he0;
        hp[1 * HSZ] = he1;
        hp[2 * HSZ] = he2;
        hp[3 * HSZ] = he3;
        hp[4 * HSZ] = tm0;
        hp[5 * HSZ] = tm1;
        hp[6 * HSZ] = tm2;
    }
    __syncthreads();

    // ---- phase 4: vertical pass (4-tall column per thread) ----
    {
        const float* colbase = hb + x * HPITCH + y0;
        float accL0[4] = {}, accL1[4] = {}, accL2[4] = {};
        float sv[4] = {};
        float v[10];

        load10(colbase + 0 * HSZ, v);
#pragma unroll
        for (int yy = 0; yy < 4; yy++) {
            float g = dot7(E[0], v + yy);
            sv[yy] = fmaf(invS4[0] * g, g, sv[yy]);
        }
        load10(colbase + 1 * HSZ, v);
#pragma unroll
        for (int yy = 0; yy < 4; yy++) {
            float g = dot7(E[1], v + yy);
            sv[yy] = fmaf(invS4[1] * g, g, sv[yy]);
            accL0[yy] -= dot7(V[0], v + yy);
        }
        load10(colbase + 2 * HSZ, v);
#pragma unroll
        for (int yy = 0; yy < 4; yy++) {
            float g = dot7(E[2], v + yy);
            sv[yy] = fmaf(invS4[2] * g, g, sv[yy]);
            accL1[yy] -= dot7(V[1], v + yy);
        }
        load10(colbase + 3 * HSZ, v);
#pragma unroll
        for (int yy = 0; yy < 4; yy++) accL2[yy] -= dot7(V[2], v + yy);
        load10(colbase + 4 * HSZ, v);
#pragma unroll
        for (int yy = 0; yy < 4; yy++) accL0[yy] += dot7(E[1], v + yy);
        load10(colbase + 5 * HSZ, v);
#pragma unroll
        for (int yy = 0; yy < 4; yy++) accL1[yy] += dot7(E[2], v + yy);
        load10(colbase + 6 * HSZ, v);
#pragma unroll
        for (int yy = 0; yy < 4; yy++) accL2[yy] += dot7(E[3], v + yy);

#pragma unroll
        for (int yy = 0; yy < 4; yy++) {
            total += sv[yy] + invN2[0] * accL0[yy] * accL0[yy] +
                     invN2[1] * accL1[yy] * accL1[yy] + invN2[2] * accL2[yy] * accL2[yy];
        }
    }

    // ---- reduction ----
    for (int off = 32; off > 0; off >>= 1) total += __shfl_down(total, off);
    int lane = tid & 63, wid = tid >> 6;
    if (lane == 0) red[wid] = total;
    __syncthreads();
    if (tid == 0) atomicAdd(&g_c[60], (red[0] + red[1]) + (red[2] + red[3]));
}

__global__ void finalize_kernel(float* __restrict__ out) {
    if (threadIdx.x == 0 && blockIdx.x == 0) out[0] = g_c[60] * (1.0f / (float)NPIX);
}

extern "C" void kernel_launch(void* const* d_in, const int* in_sizes, int n_in,
                              void* d_out, int out_size, void* d_ws, size_t ws_size,
                              hipStream_t stream) {
    const float* recon = (const float*)d_in[0];
    const float* target = (const float*)d_in[1];

    hipLaunchKernelGGL(precompute_kernel, dim3(1), dim3(64), 0, stream);
    hipLaunchKernelGGL(sum_target_kernel, dim3(2048), dim3(256), 0, stream,
                       (const float4*)target);
    dim3 grid(16, 16, 64), block(256);  // 1-D block: kernel uses flat threadIdx.x
    hipLaunchKernelGGL(main_kernel, grid, block, 0, stream, recon, target);
    hipLaunchKernelGGL(finalize_kernel, dim3(1), dim3(1), 0, stream, (float*)d_out);
}

// Round 5
// 182.695 us; speedup vs baseline: 1.5180x; 1.4805x over previous
//
#include <hip/hip_runtime.h>
#include <math.h>

#define IMG 512
#define IMG2 (IMG * IMG)
#define NPIX (64 * IMG2)
#define ZPB 8  // images per block (z-pipelined)

// constants + accumulators (rewritten deterministically every launch)
// [0..27]  E[4][7]   exp vectors for sigma {0.5,1,2,4}
// [28..48] V[3][7]   (x^2/2s^2)*E for LoG sigmas {1,2,4}
// [49..51] invS4[3]  1/gsum^2 for gaussian sigmas {0.5,1,2}
// [52..54] invN2[3]  1/norm^2 for LoG sigmas {1,2,4}
// [60] loss accumulator, [61] target-sum accumulator
__device__ float g_c[64];

__device__ __forceinline__ float rdfl(float x) {
    return __uint_as_float(__builtin_amdgcn_readfirstlane(__float_as_uint(x)));
}

__global__ void precompute_kernel() {
    if (threadIdx.x != 0 || blockIdx.x != 0) return;
    const double step = 7.0 / 6.0;
    float x[7];
    for (int j = 0; j < 7; j++) x[j] = (float)(-4.0 + j * step);
    x[6] = 3.0f;
    const float sigs[4] = {0.5f, 1.0f, 2.0f, 4.0f};
    float E[4][7], Q[4][7];
    for (int s = 0; s < 4; s++) {
        float inv = 1.0f / (2.0f * sigs[s] * sigs[s]);
        for (int j = 0; j < 7; j++) {
            float q = x[j] * x[j] * inv;
            Q[s][j] = q;
            E[s][j] = expf(-q);
        }
    }
    for (int s = 0; s < 4; s++)
        for (int j = 0; j < 7; j++) g_c[s * 7 + j] = E[s][j];
    for (int s = 1; s < 4; s++)
        for (int j = 0; j < 7; j++) g_c[28 + (s - 1) * 7 + j] = Q[s][j] * E[s][j];
    for (int s = 0; s < 3; s++) {
        float gs = 0.f;
        for (int i = 0; i < 7; i++)
            for (int j = 0; j < 7; j++) gs += E[s][i] * E[s][j];
        g_c[49 + s] = 1.0f / (gs * gs);
    }
    for (int s = 1; s < 4; s++) {
        float n = 0.f;
        for (int i = 0; i < 7; i++)
            for (int j = 0; j < 7; j++) {
                float v = E[s][i] * E[s][j] * (1.0f - Q[s][i] - Q[s][j]);
                n += fabsf(v);
            }
        g_c[52 + (s - 1)] = 1.0f / (n * n);
    }
    g_c[60] = 0.f;
    g_c[61] = 0.f;
}

__global__ __launch_bounds__(256) void sum_target_kernel(const float4* __restrict__ t4) {
    int tid = blockIdx.x * 256 + threadIdx.x;
    float s = 0.f;
    for (int i = tid; i < NPIX / 4; i += 2048 * 256) {
        float4 v = t4[i];
        s += (v.x + v.y) + (v.z + v.w);
    }
    for (int off = 32; off > 0; off >>= 1) s += __shfl_down(s, off);
    __shared__ float ps[4];
    int lane = threadIdx.x & 63, wid = threadIdx.x >> 6;
    if (lane == 0) ps[wid] = s;
    __syncthreads();
    if (threadIdx.x == 0) atomicAdd(&g_c[61], (ps[0] + ps[1]) + (ps[2] + ps[3]));
}

__device__ __forceinline__ float dot7(const float c[7], const float* v) {
    float s = c[0] * v[0];
#pragma unroll
    for (int k = 1; k < 7; k++) s = fmaf(c[k], v[k], s);
    return s;
}

__device__ __forceinline__ void load10(const float* p, float* v) {
    const float2* p2 = (const float2*)p;
#pragma unroll
    for (int q = 0; q < 5; q++) {
        float2 t = p2[q];
        v[2 * q] = t.x;
        v[2 * q + 1] = t.y;
    }
}

// LDS (separate regions, no overlay -> enables z-pipelining):
//  sd[38][40]  d = r-t; col jj = gx-(gx0-4); pixel x <-> jj = x+4
//  sr[34][40], st[34][40]  r,t for maxpool; row i' = pixelrow+1, col jj as sd
//  hb[7][32][38]  transposed horizontal-conv buffer
#define HPITCH 38
#define HSZ (32 * HPITCH)  // 1216 per filter

__global__ __launch_bounds__(256) void main_kernel(const float* __restrict__ R,
                                                   const float* __restrict__ T) {
    __shared__ float sd[38][40];
    __shared__ float sr[34][40];
    __shared__ float st[34][40];
    __shared__ float hb[7 * HSZ];
    __shared__ float red[4];

    const int tid = threadIdx.x;
    const int gx0 = blockIdx.x * 32, gy0 = blockIdx.y * 32;
    const int z0 = blockIdx.z * ZPB;

    // uniform coefficients -> SGPRs
    float E[4][7], V[3][7], invS4[3], invN2[3];
#pragma unroll
    for (int s = 0; s < 4; s++)
#pragma unroll
        for (int j = 0; j < 7; j++) E[s][j] = rdfl(g_c[s * 7 + j]);
#pragma unroll
    for (int s = 0; s < 3; s++)
#pragma unroll
        for (int j = 0; j < 7; j++) V[s][j] = rdfl(g_c[28 + s * 7 + j]);
#pragma unroll
    for (int s = 0; s < 3; s++) {
        invS4[s] = rdfl(g_c[49 + s]);
        invN2[s] = rdfl(g_c[52 + s]);
    }
    const float mean = rdfl(g_c[61]) * (1.0f / (float)NPIX);

    // ---- per-thread load geometry (z-independent) ----
    // 380 float4-quads per array: quad q -> row i = q/10, quad-col c = q%10
    const int q0 = tid, q1 = tid + 256;
    const bool has1 = (q1 < 380);
    const int i0 = q0 / 10, c0 = q0 - 10 * i0;
    const int i1 = q1 / 10, c1 = q1 - 10 * i1;
    const int gy_0 = gy0 + i0 - 3, gxb0 = gx0 - 4 + 4 * c0;
    const int gy_1 = gy0 + i1 - 3, gxb1 = gx0 - 4 + 4 * c1;
    const int o0 = min(max(gy_0, 0), IMG - 1) * IMG + min(max(gxb0, 0), IMG - 4);
    const int o1 = min(max(gy_1, 0), IMG - 1) * IMG + min(max(gxb1, 0), IMG - 4);
    const bool vy0 = ((unsigned)gy_0 < IMG), vy1 = ((unsigned)gy_1 < IMG);
    bool m0[4], m1[4];
#pragma unroll
    for (int e = 0; e < 4; e++) {
        m0[e] = vy0 && ((unsigned)(gxb0 + e) < IMG);
        m1[e] = vy1 && ((unsigned)(gxb1 + e) < IMG);
    }

    const int x = tid & 31;
    const int y0 = (tid >> 5) * 4;  // 8 groups of 4 rows -> 32 rows

    float4 ra, ta, rb, tb;  // prefetch registers

#define LOAD_TILE(zz)                                        \
    {                                                        \
        const float* Rz = R + (long)(zz)*IMG2;               \
        const float* Tz = T + (long)(zz)*IMG2;               \
        ra = *(const float4*)(Rz + o0);                      \
        ta = *(const float4*)(Tz + o0);                      \
        if (has1) {                                          \
            rb = *(const float4*)(Rz + o1);                  \
            tb = *(const float4*)(Tz + o1);                  \
        }                                                    \
    }

#define WRITE_TILE()                                                             \
    {                                                                            \
        float rv[4] = {ra.x, ra.y, ra.z, ra.w};                                  \
        float tv[4] = {ta.x, ta.y, ta.z, ta.w};                                  \
        float dq[4], rq[4], tq[4];                                               \
        _Pragma("unroll") for (int e = 0; e < 4; e++) {                          \
            dq[e] = m0[e] ? (rv[e] - tv[e]) : 0.f;                               \
            rq[e] = m0[e] ? rv[e] : -INFINITY;                                   \
            tq[e] = m0[e] ? tv[e] : -INFINITY;                                   \
        }                                                                        \
        *(float4*)&sd[i0][4 * c0] = make_float4(dq[0], dq[1], dq[2], dq[3]);     \
        if (i0 >= 2 && i0 < 36) {                                                \
            *(float4*)&sr[i0 - 2][4 * c0] = make_float4(rq[0], rq[1], rq[2], rq[3]); \
            *(float4*)&st[i0 - 2][4 * c0] = make_float4(tq[0], tq[1], tq[2], tq[3]); \
        }                                                                        \
        if (has1) {                                                              \
            float rv1[4] = {rb.x, rb.y, rb.z, rb.w};                             \
            float tv1[4] = {tb.x, tb.y, tb.z, tb.w};                             \
            float dq1[4], rq1[4], tq1[4];                                        \
            _Pragma("unroll") for (int e = 0; e < 4; e++) {                      \
                dq1[e] = m1[e] ? (rv1[e] - tv1[e]) : 0.f;                        \
                rq1[e] = m1[e] ? rv1[e] : -INFINITY;                             \
                tq1[e] = m1[e] ? tv1[e] : -INFINITY;                             \
            }                                                                    \
            *(float4*)&sd[i1][4 * c1] = make_float4(dq1[0], dq1[1], dq1[2], dq1[3]); \
            if (i1 >= 2 && i1 < 36) {                                            \
                *(float4*)&sr[i1 - 2][4 * c1] = make_float4(rq1[0], rq1[1], rq1[2], rq1[3]); \
                *(float4*)&st[i1 - 2][4 * c1] = make_float4(tq1[0], tq1[1], tq1[2], tq1[3]); \
            }                                                                    \
        }                                                                        \
    }

    // prologue: fill LDS with first tile
    LOAD_TILE(z0);
    WRITE_TILE();
    __syncthreads();

    float total = 0.f;

    for (int it = 0; it < ZPB; ++it) {
        const bool havenext = (it + 1 < ZPB);
        if (havenext) LOAD_TILE(z0 + it + 1);  // issue early; consumed after barrier

        // ---- phase 2: local terms (sobel, point, recon, maxpool) ----
        {
            float dw[6][3];
#pragma unroll
            for (int r = 0; r < 6; r++)
#pragma unroll
                for (int c = 0; c < 3; c++) dw[r][c] = sd[y0 + 2 + r][x + 3 + c];
            float rx[6], rs[6];
#pragma unroll
            for (int r = 0; r < 6; r++) {
                rx[r] = dw[r][2] - dw[r][0];
                rs[r] = dw[r][0] + 2.f * dw[r][1] + dw[r][2];
            }
            float crm[6], ctm[6], tc[6];
#pragma unroll
            for (int r = 0; r < 6; r++) {
                float a = sr[y0 + r][x + 3], b = sr[y0 + r][x + 4], c = sr[y0 + r][x + 5];
                crm[r] = fmaxf(fmaxf(a, b), c);
                float a2 = st[y0 + r][x + 3], b2 = st[y0 + r][x + 4], c2 = st[y0 + r][x + 5];
                ctm[r] = fmaxf(fmaxf(a2, b2), c2);
                tc[r] = b2;
            }
#pragma unroll
            for (int yy = 0; yy < 4; yy++) {
                float sx = rx[yy] + 2.f * rx[yy + 1] + rx[yy + 2];
                float sy = rs[yy + 2] - rs[yy];
                float pt = 4.f * dw[yy + 1][1] - dw[yy][1] - dw[yy + 2][1] - dw[yy + 1][0] -
                           dw[yy + 1][2];
                float d = dw[yy + 1][1];
                float w2 = (tc[yy + 1] > mean) ? 9.f : 1.f;
                float mr = fmaxf(fmaxf(crm[yy], crm[yy + 1]), crm[yy + 2]);
                float mt = fmaxf(fmaxf(ctm[yy], ctm[yy + 1]), ctm[yy + 2]);
                total += w2 * d * d + 2.f * (sx * sx + sy * sy) + 1.5f * pt * pt +
                         2.f * fabsf(mr - mt);
            }
        }

        // ---- phase 3: horizontal pass into transposed hb (no barrier needed:
        // hb is dead [prev ph4 reads fenced by prior sync], disjoint from ph2 reads) ----
#pragma unroll
        for (int k = 0; k < 5; ++k) {
            int pos = tid + k * 256;
            if (pos < 38 * 32) {
                int y = pos >> 5, xx = pos & 31;
                const float* row = &sd[y][xx + 1];
                float rv[7];
#pragma unroll
                for (int j = 0; j < 7; j++) rv[j] = row[j];
                float he0 = dot7(E[0], rv);
                float he1 = dot7(E[1], rv);
                float he2 = dot7(E[2], rv);
                float he3 = dot7(E[3], rv);
                float tm0 = he1 - dot7(V[0], rv);
                float tm1 = he2 - dot7(V[1], rv);
                float tm2 = he3 - dot7(V[2], rv);
                float* hp = hb + xx * HPITCH + y;
                hp[0 * HSZ] = he0;
                hp[1 * HSZ] = he1;
                hp[2 * HSZ] = he2;
                hp[3 * HSZ] = he3;
                hp[4 * HSZ] = tm0;
                hp[5 * HSZ] = tm1;
                hp[6 * HSZ] = tm2;
            }
        }
        __syncthreads();  // S1: all sd/sr/st reads + hb writes complete

        // stage next tile into LDS now (overlaps ph4's hb reads; disjoint regions)
        if (havenext) WRITE_TILE();

        // ---- phase 4: vertical pass (4-tall column per thread) ----
        {
            const float* colbase = hb + x * HPITCH + y0;
            float accL0[4] = {}, accL1[4] = {}, accL2[4] = {};
            float sv[4] = {};
            float v[10];

            load10(colbase + 0 * HSZ, v);
#pragma unroll
            for (int yy = 0; yy < 4; yy++) {
                float g = dot7(E[0], v + yy);
                sv[yy] = fmaf(invS4[0] * g, g, sv[yy]);
            }
            load10(colbase + 1 * HSZ, v);
#pragma unroll
            for (int yy = 0; yy < 4; yy++) {
                float g = dot7(E[1], v + yy);
                sv[yy] = fmaf(invS4[1] * g, g, sv[yy]);
                accL0[yy] -= dot7(V[0], v + yy);
            }
            load10(colbase + 2 * HSZ, v);
#pragma unroll
            for (int yy = 0; yy < 4; yy++) {
                float g = dot7(E[2], v + yy);
                sv[yy] = fmaf(invS4[2] * g, g, sv[yy]);
                accL1[yy] -= dot7(V[1], v + yy);
            }
            load10(colbase + 3 * HSZ, v);
#pragma unroll
            for (int yy = 0; yy < 4; yy++) accL2[yy] -= dot7(V[2], v + yy);
            load10(colbase + 4 * HSZ, v);
#pragma unroll
            for (int yy = 0; yy < 4; yy++) accL0[yy] += dot7(E[1], v + yy);
            load10(colbase + 5 * HSZ, v);
#pragma unroll
            for (int yy = 0; yy < 4; yy++) accL1[yy] += dot7(E[2], v + yy);
            load10(colbase + 6 * HSZ, v);
#pragma unroll
            for (int yy = 0; yy < 4; yy++) accL2[yy] += dot7(E[3], v + yy);

#pragma unroll
            for (int yy = 0; yy < 4; yy++) {
                total += sv[yy] + invN2[0] * accL0[yy] * accL0[yy] +
                         invN2[1] * accL1[yy] * accL1[yy] + invN2[2] * accL2[yy] * accL2[yy];
            }
        }
        __syncthreads();  // S2: next-tile LDS writes visible; hb reads done
    }

    // ---- reduction ----
    for (int off = 32; off > 0; off >>= 1) total += __shfl_down(total, off);
    int lane = tid & 63, wid = tid >> 6;
    if (lane == 0) red[wid] = total;
    __syncthreads();
    if (tid == 0) atomicAdd(&g_c[60], (red[0] + red[1]) + (red[2] + red[3]));
}

__global__ void finalize_kernel(float* __restrict__ out) {
    if (threadIdx.x == 0 && blockIdx.x == 0) out[0] = g_c[60] * (1.0f / (float)NPIX);
}

extern "C" void kernel_launch(void* const* d_in, const int* in_sizes, int n_in,
                              void* d_out, int out_size, void* d_ws, size_t ws_size,
                              hipStream_t stream) {
    const float* recon = (const float*)d_in[0];
    const float* target = (const float*)d_in[1];

    hipLaunchKernelGGL(precompute_kernel, dim3(1), dim3(64), 0, stream);
    hipLaunchKernelGGL(sum_target_kernel, dim3(2048), dim3(256), 0, stream,
                       (const float4*)target);
    dim3 grid(16, 16, 64 / ZPB), block(256);
    hipLaunchKernelGGL(main_kernel, grid, block, 0, stream, recon, target);
    hipLaunchKernelGGL(finalize_kernel, dim3(1), dim3(1), 0, stream, (float*)d_out);
}

// Round 6
// 171.969 us; speedup vs baseline: 1.6127x; 1.0624x over previous
//
#include <hip/hip_runtime.h>
#include <math.h>

#define IMG 512
#define IMG2 (IMG * IMG)
#define NPIX (64 * IMG2)
#define ZPB 8  // images per block (z-pipelined)

// constants + accumulators (rewritten deterministically every launch)
__device__ float g_c[64];

__device__ __forceinline__ float rdfl(float x) {
    return __uint_as_float(__builtin_amdgcn_readfirstlane(__float_as_uint(x)));
}

__global__ void precompute_kernel() {
    if (threadIdx.x != 0 || blockIdx.x != 0) return;
    const double step = 7.0 / 6.0;
    float x[7];
    for (int j = 0; j < 7; j++) x[j] = (float)(-4.0 + j * step);
    x[6] = 3.0f;
    const float sigs[4] = {0.5f, 1.0f, 2.0f, 4.0f};
    float E[4][7], Q[4][7];
    for (int s = 0; s < 4; s++) {
        float inv = 1.0f / (2.0f * sigs[s] * sigs[s]);
        for (int j = 0; j < 7; j++) {
            float q = x[j] * x[j] * inv;
            Q[s][j] = q;
            E[s][j] = expf(-q);
        }
    }
    for (int s = 0; s < 4; s++)
        for (int j = 0; j < 7; j++) g_c[s * 7 + j] = E[s][j];
    for (int s = 1; s < 4; s++)
        for (int j = 0; j < 7; j++) g_c[28 + (s - 1) * 7 + j] = Q[s][j] * E[s][j];
    for (int s = 0; s < 3; s++) {
        float gs = 0.f;
        for (int i = 0; i < 7; i++)
            for (int j = 0; j < 7; j++) gs += E[s][i] * E[s][j];
        g_c[49 + s] = 1.0f / (gs * gs);
    }
    for (int s = 1; s < 4; s++) {
        float n = 0.f;
        for (int i = 0; i < 7; i++)
            for (int j = 0; j < 7; j++) {
                float v = E[s][i] * E[s][j] * (1.0f - Q[s][i] - Q[s][j]);
                n += fabsf(v);
            }
        g_c[52 + (s - 1)] = 1.0f / (n * n);
    }
    g_c[60] = 0.f;
    g_c[61] = 0.f;
}

__global__ __launch_bounds__(256) void sum_target_kernel(const float4* __restrict__ t4) {
    int tid = blockIdx.x * 256 + threadIdx.x;
    float s = 0.f;
    for (int i = tid; i < NPIX / 4; i += 2048 * 256) {
        float4 v = t4[i];
        s += (v.x + v.y) + (v.z + v.w);
    }
    for (int off = 32; off > 0; off >>= 1) s += __shfl_down(s, off);
    __shared__ float ps[4];
    int lane = threadIdx.x & 63, wid = threadIdx.x >> 6;
    if (lane == 0) ps[wid] = s;
    __syncthreads();
    if (threadIdx.x == 0) atomicAdd(&g_c[61], (ps[0] + ps[1]) + (ps[2] + ps[3]));
}

__device__ __forceinline__ float dot7(const float c[7], const float* v) {
    float s = c[0] * v[0];
#pragma unroll
    for (int k = 1; k < 7; k++) s = fmaf(c[k], v[k], s);
    return s;
}
__device__ __forceinline__ float dot7x(const float c[7], const float2* v) {
    float s = c[0] * v[0].x;
#pragma unroll
    for (int k = 1; k < 7; k++) s = fmaf(c[k], v[k].x, s);
    return s;
}
__device__ __forceinline__ float dot7y(const float c[7], const float2* v) {
    float s = c[0] * v[0].y;
#pragma unroll
    for (int k = 1; k < 7; k++) s = fmaf(c[k], v[k].y, s);
    return s;
}

// CPITCH odd (39): bank = (7x + y) mod 32 is bijective in x -> conflict-free
// column access for both the transposed writes (phase3) and reads (phase4).
#define CPITCH 39

__global__ __launch_bounds__(256) void main_kernel(const float* __restrict__ R,
                                                   const float* __restrict__ T) {
    __shared__ float sd[38][40];          // d = r-t; pixel x <-> col jj = x+4
    __shared__ float sr[34][40];          // r (-inf padded), rows = pixelrow+1
    __shared__ float st[34][40];          // t (-inf padded)
    __shared__ float2 p01[32][CPITCH];    // {he0, he1} transposed
    __shared__ float2 p23[32][CPITCH];    // {he2, he3}
    __shared__ float2 p45[32][CPITCH];    // {tm0, tm1}
    __shared__ float s6[32][CPITCH];      // tm2
    __shared__ float red[4];

    const int tid = threadIdx.x;
    const int gx0 = blockIdx.x * 32, gy0 = blockIdx.y * 32;
    const int z0 = blockIdx.z * ZPB;

    // uniform coefficients -> SGPRs
    float E[4][7], V[3][7], invS4[3], invN2[3];
#pragma unroll
    for (int s = 0; s < 4; s++)
#pragma unroll
        for (int j = 0; j < 7; j++) E[s][j] = rdfl(g_c[s * 7 + j]);
#pragma unroll
    for (int s = 0; s < 3; s++)
#pragma unroll
        for (int j = 0; j < 7; j++) V[s][j] = rdfl(g_c[28 + s * 7 + j]);
#pragma unroll
    for (int s = 0; s < 3; s++) {
        invS4[s] = rdfl(g_c[49 + s]);
        invN2[s] = rdfl(g_c[52 + s]);
    }
    const float mean = rdfl(g_c[61]) * (1.0f / (float)NPIX);

    // ---- per-thread load geometry (z-independent) ----
    const int q0 = tid, q1 = tid + 256;
    const bool has1 = (q1 < 380);
    const int i0 = q0 / 10, c0 = q0 - 10 * i0;
    const int i1 = q1 / 10, c1 = q1 - 10 * i1;
    const int gy_0 = gy0 + i0 - 3, gxb0 = gx0 - 4 + 4 * c0;
    const int gy_1 = gy0 + i1 - 3, gxb1 = gx0 - 4 + 4 * c1;
    const int o0 = min(max(gy_0, 0), IMG - 1) * IMG + min(max(gxb0, 0), IMG - 4);
    const int o1 = min(max(gy_1, 0), IMG - 1) * IMG + min(max(gxb1, 0), IMG - 4);
    const bool vy0 = ((unsigned)gy_0 < IMG), vy1 = ((unsigned)gy_1 < IMG);
    bool m0[4], m1[4];
#pragma unroll
    for (int e = 0; e < 4; e++) {
        m0[e] = vy0 && ((unsigned)(gxb0 + e) < IMG);
        m1[e] = vy1 && ((unsigned)(gxb1 + e) < IMG);
    }

    const int x = tid & 31;
    const int y0 = (tid >> 5) * 4;

    float4 ra, ta, rb, tb;  // prefetch registers

#define LOAD_TILE(zz)                          \
    {                                          \
        const float* Rz = R + (long)(zz)*IMG2; \
        const float* Tz = T + (long)(zz)*IMG2; \
        ra = *(const float4*)(Rz + o0);        \
        ta = *(const float4*)(Tz + o0);        \
        if (has1) {                            \
            rb = *(const float4*)(Rz + o1);    \
            tb = *(const float4*)(Tz + o1);    \
        }                                      \
    }

#define WRITE_TILE()                                                                         \
    {                                                                                        \
        float rv[4] = {ra.x, ra.y, ra.z, ra.w};                                              \
        float tv[4] = {ta.x, ta.y, ta.z, ta.w};                                              \
        float dq[4], rq[4], tq[4];                                                           \
        _Pragma("unroll") for (int e = 0; e < 4; e++) {                                      \
            dq[e] = m0[e] ? (rv[e] - tv[e]) : 0.f;                                           \
            rq[e] = m0[e] ? rv[e] : -INFINITY;                                               \
            tq[e] = m0[e] ? tv[e] : -INFINITY;                                               \
        }                                                                                    \
        *(float4*)&sd[i0][4 * c0] = make_float4(dq[0], dq[1], dq[2], dq[3]);                 \
        if (i0 >= 2 && i0 < 36) {                                                            \
            *(float4*)&sr[i0 - 2][4 * c0] = make_float4(rq[0], rq[1], rq[2], rq[3]);         \
            *(float4*)&st[i0 - 2][4 * c0] = make_float4(tq[0], tq[1], tq[2], tq[3]);         \
        }                                                                                    \
        if (has1) {                                                                          \
            float rv1[4] = {rb.x, rb.y, rb.z, rb.w};                                         \
            float tv1[4] = {tb.x, tb.y, tb.z, tb.w};                                         \
            float dq1[4], rq1[4], tq1[4];                                                    \
            _Pragma("unroll") for (int e = 0; e < 4; e++) {                                  \
                dq1[e] = m1[e] ? (rv1[e] - tv1[e]) : 0.f;                                    \
                rq1[e] = m1[e] ? rv1[e] : -INFINITY;                                         \
                tq1[e] = m1[e] ? tv1[e] : -INFINITY;                                         \
            }                                                                                \
            *(float4*)&sd[i1][4 * c1] = make_float4(dq1[0], dq1[1], dq1[2], dq1[3]);         \
            if (i1 >= 2 && i1 < 36) {                                                        \
                *(float4*)&sr[i1 - 2][4 * c1] = make_float4(rq1[0], rq1[1], rq1[2], rq1[3]); \
                *(float4*)&st[i1 - 2][4 * c1] = make_float4(tq1[0], tq1[1], tq1[2], tq1[3]); \
            }                                                                                \
        }                                                                                    \
    }

    LOAD_TILE(z0);
    WRITE_TILE();
    __syncthreads();

    float total = 0.f;

    for (int it = 0; it < ZPB; ++it) {
        const bool havenext = (it + 1 < ZPB);
        if (havenext) LOAD_TILE(z0 + it + 1);  // issue early; consumed after S1

        // ---- phase 2: local terms (sobel, point, recon, maxpool) ----
        {
            float dw[6][3];
#pragma unroll
            for (int r = 0; r < 6; r++)
#pragma unroll
                for (int c = 0; c < 3; c++) dw[r][c] = sd[y0 + 2 + r][x + 3 + c];
            float rx[6], rs[6];
#pragma unroll
            for (int r = 0; r < 6; r++) {
                rx[r] = dw[r][2] - dw[r][0];
                rs[r] = dw[r][0] + 2.f * dw[r][1] + dw[r][2];
            }
            float crm[6], ctm[6], tc[6];
#pragma unroll
            for (int r = 0; r < 6; r++) {
                float a = sr[y0 + r][x + 3], b = sr[y0 + r][x + 4], c = sr[y0 + r][x + 5];
                crm[r] = fmaxf(fmaxf(a, b), c);
                float a2 = st[y0 + r][x + 3], b2 = st[y0 + r][x + 4], c2 = st[y0 + r][x + 5];
                ctm[r] = fmaxf(fmaxf(a2, b2), c2);
                tc[r] = b2;
            }
#pragma unroll
            for (int yy = 0; yy < 4; yy++) {
                float sx = rx[yy] + 2.f * rx[yy + 1] + rx[yy + 2];
                float sy = rs[yy + 2] - rs[yy];
                float pt = 4.f * dw[yy + 1][1] - dw[yy][1] - dw[yy + 2][1] - dw[yy + 1][0] -
                           dw[yy + 1][2];
                float d = dw[yy + 1][1];
                float w2 = (tc[yy + 1] > mean) ? 9.f : 1.f;
                float mr = fmaxf(fmaxf(crm[yy], crm[yy + 1]), crm[yy + 2]);
                float mt = fmaxf(fmaxf(ctm[yy], ctm[yy + 1]), ctm[yy + 2]);
                total += w2 * d * d + 2.f * (sx * sx + sy * sy) + 1.5f * pt * pt +
                         2.f * fabsf(mr - mt);
            }
        }

        // ---- phase 3: horizontal pass, job = (row y, xx-quad), 304 jobs ----
        for (int j = tid; j < 304; j += 256) {
            int y = j >> 3, xq = j & 7;
            const float* rp = &sd[y][4 * xq];
            float4 A = *(const float4*)(rp);
            float4 B = *(const float4*)(rp + 4);
            float4 C = *(const float4*)(rp + 8);
            float rv[12] = {A.x, A.y, A.z, A.w, B.x, B.y, B.z, B.w, C.x, C.y, C.z, C.w};
#pragma unroll
            for (int p = 0; p < 4; p++) {
                const float* w = rv + p + 1;  // taps jj = xx+1 .. xx+7
                float he0 = dot7(E[0], w);
                float he1 = dot7(E[1], w);
                float he2 = dot7(E[2], w);
                float he3 = dot7(E[3], w);
                float tm0 = he1 - dot7(V[0], w);
                float tm1 = he2 - dot7(V[1], w);
                float tm2 = he3 - dot7(V[2], w);
                int xx = 4 * xq + p;
                p01[xx][y] = make_float2(he0, he1);
                p23[xx][y] = make_float2(he2, he3);
                p45[xx][y] = make_float2(tm0, tm1);
                s6[xx][y] = tm2;
            }
        }
        __syncthreads();  // S1: sd/sr/st reads + plane writes complete

        if (havenext) WRITE_TILE();  // stage next tile (disjoint from planes)

        // ---- phase 4: vertical pass (4-tall column per thread) ----
        {
            float sv[4] = {}, accL0[4] = {}, accL1[4] = {}, accL2[4] = {};
            float2 cb[10];
#pragma unroll
            for (int q = 0; q < 10; q++) cb[q] = p01[x][y0 + q];
#pragma unroll
            for (int yy = 0; yy < 4; yy++) {
                float g0 = dot7x(E[0], cb + yy);
                sv[yy] = fmaf(invS4[0] * g0, g0, sv[yy]);
                float g1 = dot7y(E[1], cb + yy);
                sv[yy] = fmaf(invS4[1] * g1, g1, sv[yy]);
                accL0[yy] -= dot7y(V[0], cb + yy);
            }
#pragma unroll
            for (int q = 0; q < 10; q++) cb[q] = p23[x][y0 + q];
#pragma unroll
            for (int yy = 0; yy < 4; yy++) {
                float g2 = dot7x(E[2], cb + yy);
                sv[yy] = fmaf(invS4[2] * g2, g2, sv[yy]);
                accL1[yy] -= dot7x(V[1], cb + yy);
                accL2[yy] -= dot7y(V[2], cb + yy);
            }
#pragma unroll
            for (int q = 0; q < 10; q++) cb[q] = p45[x][y0 + q];
#pragma unroll
            for (int yy = 0; yy < 4; yy++) {
                accL0[yy] += dot7x(E[1], cb + yy);
                accL1[yy] += dot7y(E[2], cb + yy);
            }
            float s6b[10];
#pragma unroll
            for (int q = 0; q < 10; q++) s6b[q] = s6[x][y0 + q];
#pragma unroll
            for (int yy = 0; yy < 4; yy++) accL2[yy] += dot7(E[3], s6b + yy);

#pragma unroll
            for (int yy = 0; yy < 4; yy++) {
                total += sv[yy] + invN2[0] * accL0[yy] * accL0[yy] +
                         invN2[1] * accL1[yy] * accL1[yy] + invN2[2] * accL2[yy] * accL2[yy];
            }
        }
        __syncthreads();  // S2: next-tile LDS writes visible; plane reads done
    }

    // ---- reduction ----
    for (int off = 32; off > 0; off >>= 1) total += __shfl_down(total, off);
    int lane = tid & 63, wid = tid >> 6;
    if (lane == 0) red[wid] = total;
    __syncthreads();
    if (tid == 0) atomicAdd(&g_c[60], (red[0] + red[1]) + (red[2] + red[3]));
}

__global__ void finalize_kernel(float* __restrict__ out) {
    if (threadIdx.x == 0 && blockIdx.x == 0) out[0] = g_c[60] * (1.0f / (float)NPIX);
}

extern "C" void kernel_launch(void* const* d_in, const int* in_sizes, int n_in,
                              void* d_out, int out_size, void* d_ws, size_t ws_size,
                              hipStream_t stream) {
    const float* recon = (const float*)d_in[0];
    const float* target = (const float*)d_in[1];

    hipLaunchKernelGGL(precompute_kernel, dim3(1), dim3(64), 0, stream);
    hipLaunchKernelGGL(sum_target_kernel, dim3(2048), dim3(256), 0, stream,
                       (const float4*)target);
    dim3 grid(16, 16, 64 / ZPB), block(256);
    hipLaunchKernelGGL(main_kernel, grid, block, 0, stream, recon, target);
    hipLaunchKernelGGL(finalize_kernel, dim3(1), dim3(1), 0, stream, (float*)d_out);
}

// Round 8
// 164.657 us; speedup vs baseline: 1.6843x; 1.0444x over previous
//
#include <hip/hip_runtime.h>
#include <math.h>

#define IMG 512
#define IMG2 (IMG * IMG)
#define NPIX (64 * IMG2)
#define ZPB 16  // images per block (z-pipelined); grid z = 64/ZPB = 4 -> 1024 blocks = 4/CU

// constants + accumulators (rewritten deterministically every launch)
__device__ float g_c[64];

__device__ __forceinline__ float rdfl(float x) {
    return __uint_as_float(__builtin_amdgcn_readfirstlane(__float_as_uint(x)));
}

typedef __fp16 h2_t __attribute__((ext_vector_type(2)));

__device__ __forceinline__ unsigned int pkrtz(float a, float b) {
    h2_t v = __builtin_amdgcn_cvt_pkrtz(a, b);
    union { h2_t h; unsigned int u; } cv;
    cv.h = v;
    return cv.u;
}
__device__ __forceinline__ float2 unpk(unsigned int u) {
    union { unsigned int u; h2_t h; } cv;
    cv.u = u;
    return make_float2((float)cv.h[0], (float)cv.h[1]);
}

__global__ void precompute_kernel() {
    if (threadIdx.x != 0 || blockIdx.x != 0) return;
    const double step = 7.0 / 6.0;
    float x[7];
    for (int j = 0; j < 7; j++) x[j] = (float)(-4.0 + j * step);
    x[6] = 3.0f;
    const float sigs[4] = {0.5f, 1.0f, 2.0f, 4.0f};
    float E[4][7], Q[4][7];
    for (int s = 0; s < 4; s++) {
        float inv = 1.0f / (2.0f * sigs[s] * sigs[s]);
        for (int j = 0; j < 7; j++) {
            float q = x[j] * x[j] * inv;
            Q[s][j] = q;
            E[s][j] = expf(-q);
        }
    }
    for (int s = 0; s < 4; s++)
        for (int j = 0; j < 7; j++) g_c[s * 7 + j] = E[s][j];
    for (int s = 1; s < 4; s++)
        for (int j = 0; j < 7; j++) g_c[28 + (s - 1) * 7 + j] = Q[s][j] * E[s][j];
    for (int s = 0; s < 3; s++) {
        float gs = 0.f;
        for (int i = 0; i < 7; i++)
            for (int j = 0; j < 7; j++) gs += E[s][i] * E[s][j];
        g_c[49 + s] = 1.0f / (gs * gs);
    }
    for (int s = 1; s < 4; s++) {
        float n = 0.f;
        for (int i = 0; i < 7; i++)
            for (int j = 0; j < 7; j++) {
                float v = E[s][i] * E[s][j] * (1.0f - Q[s][i] - Q[s][j]);
                n += fabsf(v);
            }
        g_c[52 + (s - 1)] = 1.0f / (n * n);
    }
    g_c[60] = 0.f;
    g_c[61] = 0.f;
}

__global__ __launch_bounds__(256) void sum_target_kernel(const float4* __restrict__ t4) {
    int tid = blockIdx.x * 256 + threadIdx.x;
    float s = 0.f;
    for (int i = tid; i < NPIX / 4; i += 2048 * 256) {
        float4 v = t4[i];
        s += (v.x + v.y) + (v.z + v.w);
    }
    for (int off = 32; off > 0; off >>= 1) s += __shfl_down(s, off);
    __shared__ float ps[4];
    int lane = threadIdx.x & 63, wid = threadIdx.x >> 6;
    if (lane == 0) ps[wid] = s;
    __syncthreads();
    if (threadIdx.x == 0) atomicAdd(&g_c[61], (ps[0] + ps[1]) + (ps[2] + ps[3]));
}

__device__ __forceinline__ float dot7(const float c[7], const float* v) {
    float s = c[0] * v[0];
#pragma unroll
    for (int k = 1; k < 7; k++) s = fmaf(c[k], v[k], s);
    return s;
}

__global__ __launch_bounds__(256, 4) void main_kernel(const float* __restrict__ R,
                                                      const float* __restrict__ T) {
    __shared__ float sd[38][40];        // d = r-t; pixel x <-> col jj = x+4
    __shared__ float sr[34][40];        // r (-inf padded), rows = pixelrow+1
    __shared__ float st[34][40];        // t (-inf padded)
    __shared__ uint4 hrec[32][39];      // transposed h record: 8 halves
                                        // {he0,he1 | he2,he3 | tm0,tm1 | tm2,-}
    __shared__ float red[4];

    const int tid = threadIdx.x;
    const int gx0 = blockIdx.x * 32, gy0 = blockIdx.y * 32;
    const int z0 = blockIdx.z * ZPB;

    // uniform coefficients -> SGPRs
    float E[4][7], V[3][7], invS4[3], invN2[3];
#pragma unroll
    for (int s = 0; s < 4; s++)
#pragma unroll
        for (int j = 0; j < 7; j++) E[s][j] = rdfl(g_c[s * 7 + j]);
#pragma unroll
    for (int s = 0; s < 3; s++)
#pragma unroll
        for (int j = 0; j < 7; j++) V[s][j] = rdfl(g_c[28 + s * 7 + j]);
#pragma unroll
    for (int s = 0; s < 3; s++) {
        invS4[s] = rdfl(g_c[49 + s]);
        invN2[s] = rdfl(g_c[52 + s]);
    }
    const float mean = rdfl(g_c[61]) * (1.0f / (float)NPIX);

    // ---- per-thread load geometry (z-independent) ----
    const int q0 = tid, q1 = tid + 256;
    const bool has1 = (q1 < 380);
    const int i0 = q0 / 10, c0 = q0 - 10 * i0;
    const int i1 = q1 / 10, c1 = q1 - 10 * i1;
    const int gy_0 = gy0 + i0 - 3, gxb0 = gx0 - 4 + 4 * c0;
    const int gy_1 = gy0 + i1 - 3, gxb1 = gx0 - 4 + 4 * c1;
    const int o0 = min(max(gy_0, 0), IMG - 1) * IMG + min(max(gxb0, 0), IMG - 4);
    const int o1 = min(max(gy_1, 0), IMG - 1) * IMG + min(max(gxb1, 0), IMG - 4);
    const bool vy0 = ((unsigned)gy_0 < IMG), vy1 = ((unsigned)gy_1 < IMG);
    bool m0[4], m1[4];
#pragma unroll
    for (int e = 0; e < 4; e++) {
        m0[e] = vy0 && ((unsigned)(gxb0 + e) < IMG);
        m1[e] = vy1 && ((unsigned)(gxb1 + e) < IMG);
    }

    const int x = tid & 31;
    const int y0 = (tid >> 5) * 4;

    float4 ra, ta, rb, tb;  // prefetch registers

#define LOAD_TILE(zz)                          \
    {                                          \
        const float* Rz = R + (long)(zz)*IMG2; \
        const float* Tz = T + (long)(zz)*IMG2; \
        ra = *(const float4*)(Rz + o0);        \
        ta = *(const float4*)(Tz + o0);        \
        if (has1) {                            \
            rb = *(const float4*)(Rz + o1);    \
            tb = *(const float4*)(Tz + o1);    \
        }                                      \
    }

#define WRITE_TILE()                                                                         \
    {                                                                                        \
        float rv[4] = {ra.x, ra.y, ra.z, ra.w};                                              \
        float tv[4] = {ta.x, ta.y, ta.z, ta.w};                                              \
        float dq[4], rq[4], tq[4];                                                           \
        _Pragma("unroll") for (int e = 0; e < 4; e++) {                                      \
            dq[e] = m0[e] ? (rv[e] - tv[e]) : 0.f;                                           \
            rq[e] = m0[e] ? rv[e] : -INFINITY;                                               \
            tq[e] = m0[e] ? tv[e] : -INFINITY;                                               \
        }                                                                                    \
        *(float4*)&sd[i0][4 * c0] = make_float4(dq[0], dq[1], dq[2], dq[3]);                 \
        if (i0 >= 2 && i0 < 36) {                                                            \
            *(float4*)&sr[i0 - 2][4 * c0] = make_float4(rq[0], rq[1], rq[2], rq[3]);         \
            *(float4*)&st[i0 - 2][4 * c0] = make_float4(tq[0], tq[1], tq[2], tq[3]);         \
        }                                                                                    \
        if (has1) {                                                                          \
            float rv1[4] = {rb.x, rb.y, rb.z, rb.w};                                         \
            float tv1[4] = {tb.x, tb.y, tb.z, tb.w};                                         \
            float dq1[4], rq1[4], tq1[4];                                                    \
            _Pragma("unroll") for (int e = 0; e < 4; e++) {                                  \
                dq1[e] = m1[e] ? (rv1[e] - tv1[e]) : 0.f;                                    \
                rq1[e] = m1[e] ? rv1[e] : -INFINITY;                                         \
                tq1[e] = m1[e] ? tv1[e] : -INFINITY;                                         \
            }                                                                                \
            *(float4*)&sd[i1][4 * c1] = make_float4(dq1[0], dq1[1], dq1[2], dq1[3]);         \
            if (i1 >= 2 && i1 < 36) {                                                        \
                *(float4*)&sr[i1 - 2][4 * c1] = make_float4(rq1[0], rq1[1], rq1[2], rq1[3]); \
                *(float4*)&st[i1 - 2][4 * c1] = make_float4(tq1[0], tq1[1], tq1[2], tq1[3]); \
            }                                                                                \
        }                                                                                    \
    }

    LOAD_TILE(z0);
    WRITE_TILE();
    __syncthreads();

    float total = 0.f;

    for (int it = 0; it < ZPB; ++it) {
        const bool havenext = (it + 1 < ZPB);
        if (havenext) LOAD_TILE(z0 + it + 1);  // issue early; consumed after S1

        // ---- phase 2: local terms (sobel, point, recon, maxpool) ----
        {
            float dw[6][3];
#pragma unroll
            for (int r = 0; r < 6; r++)
#pragma unroll
                for (int c = 0; c < 3; c++) dw[r][c] = sd[y0 + 2 + r][x + 3 + c];
            float rx[6], rs[6];
#pragma unroll
            for (int r = 0; r < 6; r++) {
                rx[r] = dw[r][2] - dw[r][0];
                rs[r] = dw[r][0] + 2.f * dw[r][1] + dw[r][2];
            }
            float crm[6], ctm[6], tc[6];
#pragma unroll
            for (int r = 0; r < 6; r++) {
                float a = sr[y0 + r][x + 3], b = sr[y0 + r][x + 4], c = sr[y0 + r][x + 5];
                crm[r] = fmaxf(fmaxf(a, b), c);
                float a2 = st[y0 + r][x + 3], b2 = st[y0 + r][x + 4], c2 = st[y0 + r][x + 5];
                ctm[r] = fmaxf(fmaxf(a2, b2), c2);
                tc[r] = b2;
            }
#pragma unroll
            for (int yy = 0; yy < 4; yy++) {
                float sx = rx[yy] + 2.f * rx[yy + 1] + rx[yy + 2];
                float sy = rs[yy + 2] - rs[yy];
                float pt = 4.f * dw[yy + 1][1] - dw[yy][1] - dw[yy + 2][1] - dw[yy + 1][0] -
                           dw[yy + 1][2];
                float d = dw[yy + 1][1];
                float w2 = (tc[yy + 1] > mean) ? 9.f : 1.f;
                float mr = fmaxf(fmaxf(crm[yy], crm[yy + 1]), crm[yy + 2]);
                float mt = fmaxf(fmaxf(ctm[yy], ctm[yy + 1]), ctm[yy + 2]);
                total += w2 * d * d + 2.f * (sx * sx + sy * sy) + 1.5f * pt * pt +
                         2.f * fabsf(mr - mt);
            }
        }

        // ---- phase 3: horizontal pass, job = (row y, xx-quad), 304 jobs ----
        for (int j = tid; j < 304; j += 256) {
            int y = j >> 3, xq = j & 7;
            const float* rp = &sd[y][4 * xq];
            float4 A = *(const float4*)(rp);
            float4 B = *(const float4*)(rp + 4);
            float4 C = *(const float4*)(rp + 8);
            float rv[12] = {A.x, A.y, A.z, A.w, B.x, B.y, B.z, B.w, C.x, C.y, C.z, C.w};
#pragma unroll
            for (int p = 0; p < 4; p++) {
                const float* w = rv + p + 1;  // taps jj = xx+1 .. xx+7
                float he0 = dot7(E[0], w);
                float he1 = dot7(E[1], w);
                float he2 = dot7(E[2], w);
                float he3 = dot7(E[3], w);
                float tm0 = he1 - dot7(V[0], w);
                float tm1 = he2 - dot7(V[1], w);
                float tm2 = he3 - dot7(V[2], w);
                hrec[4 * xq + p][y] = make_uint4(pkrtz(he0, he1), pkrtz(he2, he3),
                                                 pkrtz(tm0, tm1), pkrtz(tm2, 0.f));
            }
        }
        __syncthreads();  // S1: sd/sr/st reads + hrec writes complete

        if (havenext) WRITE_TILE();  // stage next tile (disjoint from hrec)

        // ---- phase 4: vertical pass, rolling accumulate over 10 h-rows ----
        {
            float g0[4] = {}, g1[4] = {}, g2[4] = {};
            float aL0[4] = {}, aL1[4] = {}, aL2[4] = {};
#pragma unroll
            for (int q = 0; q < 10; q++) {
                uint4 rec = hrec[x][y0 + q];
                float2 e01 = unpk(rec.x);
                float2 e23 = unpk(rec.y);
                float2 t01 = unpk(rec.z);
                float t2 = unpk(rec.w).x;
#pragma unroll
                for (int yy = 0; yy < 4; yy++) {
                    const int k = q - yy;
                    if (k >= 0 && k <= 6) {
                        g0[yy] = fmaf(E[0][k], e01.x, g0[yy]);
                        g1[yy] = fmaf(E[1][k], e01.y, g1[yy]);
                        g2[yy] = fmaf(E[2][k], e23.x, g2[yy]);
                        aL0[yy] = fmaf(-V[0][k], e01.y, aL0[yy]);
                        aL1[yy] = fmaf(-V[1][k], e23.x, aL1[yy]);
                        aL2[yy] = fmaf(-V[2][k], e23.y, aL2[yy]);
                        aL0[yy] = fmaf(E[1][k], t01.x, aL0[yy]);
                        aL1[yy] = fmaf(E[2][k], t01.y, aL1[yy]);
                        aL2[yy] = fmaf(E[3][k], t2, aL2[yy]);
                    }
                }
            }
#pragma unroll
            for (int yy = 0; yy < 4; yy++) {
                total += invS4[0] * g0[yy] * g0[yy] + invS4[1] * g1[yy] * g1[yy] +
                         invS4[2] * g2[yy] * g2[yy] + invN2[0] * aL0[yy] * aL0[yy] +
                         invN2[1] * aL1[yy] * aL1[yy] + invN2[2] * aL2[yy] * aL2[yy];
            }
        }
        __syncthreads();  // S2: next-tile LDS writes visible; hrec reads done
    }

    // ---- reduction ----
    for (int off = 32; off > 0; off >>= 1) total += __shfl_down(total, off);
    int lane = tid & 63, wid = tid >> 6;
    if (lane == 0) red[wid] = total;
    __syncthreads();
    if (tid == 0) atomicAdd(&g_c[60], (red[0] + red[1]) + (red[2] + red[3]));
}

__global__ void finalize_kernel(float* __restrict__ out) {
    if (threadIdx.x == 0 && blockIdx.x == 0) out[0] = g_c[60] * (1.0f / (float)NPIX);
}

extern "C" void kernel_launch(void* const* d_in, const int* in_sizes, int n_in,
                              void* d_out, int out_size, void* d_ws, size_t ws_size,
                              hipStream_t stream) {
    const float* recon = (const float*)d_in[0];
    const float* target = (const float*)d_in[1];

    hipLaunchKernelGGL(precompute_kernel, dim3(1), dim3(64), 0, stream);
    hipLaunchKernelGGL(sum_target_kernel, dim3(2048), dim3(256), 0, stream,
                       (const float4*)target);
    dim3 grid(16, 16, 64 / ZPB), block(256);
    hipLaunchKernelGGL(main_kernel, grid, block, 0, stream, recon, target);
    hipLaunchKernelGGL(finalize_kernel, dim3(1), dim3(1), 0, stream, (float*)d_out);
}

// Round 9
// 130.013 us; speedup vs baseline: 2.1331x; 1.2665x over previous
//
#include <hip/hip_runtime.h>
#include <math.h>

#define IMG 512
#define IMG2 (IMG * IMG)
#define NPIX (64 * IMG2)
#define ZPB 16  // images per block; grid z = 4 -> 1024 blocks = 4/CU

// g_c layout:
// [0..6]   cE01 = pk(E0,E1)   [7..13]  cE23 = pk(E2,E3)
// [14..20] cV01 = pk(V0,V1)   [21..27] cV2  = pk(V2,V2)
// [28..34] d2 = pk(E1,E2)     [35..41] d3 = pk(E2,-V2)
// [42..48] d4 = pk(-V0,-V1)   [49..55] d5 = pk(E3,0)
// [56..58] invS4, [59..61] invN2, [62] loss accum, [63] target sum
__device__ float g_c[64];

typedef __fp16 h2_t __attribute__((ext_vector_type(2)));

__device__ __forceinline__ float rdfl(float x) {
    return __uint_as_float(__builtin_amdgcn_readfirstlane(__float_as_uint(x)));
}
__device__ __forceinline__ unsigned int rdflu(float x) {
    return __builtin_amdgcn_readfirstlane(__float_as_uint(x));
}
__device__ __forceinline__ unsigned int as_u(h2_t h) {
    union { h2_t h; unsigned int u; } c;
    c.h = h;
    return c.u;
}
__device__ __forceinline__ h2_t as_h2(unsigned int u) {
    union { unsigned int u; h2_t h; } c;
    c.u = u;
    return c.h;
}
__device__ __forceinline__ h2_t h2z() {
    h2_t z = {(__fp16)0.f, (__fp16)0.f};
    return z;
}

__global__ void precompute_kernel() {
    if (threadIdx.x != 0 || blockIdx.x != 0) return;
    const double step = 7.0 / 6.0;
    float x[7];
    for (int j = 0; j < 7; j++) x[j] = (float)(-4.0 + j * step);
    x[6] = 3.0f;
    const float sigs[4] = {0.5f, 1.0f, 2.0f, 4.0f};
    float E[4][7], Q[4][7], Vv[3][7];
    for (int s = 0; s < 4; s++) {
        float inv = 1.0f / (2.0f * sigs[s] * sigs[s]);
        for (int j = 0; j < 7; j++) {
            float q = x[j] * x[j] * inv;
            Q[s][j] = q;
            E[s][j] = expf(-q);
        }
    }
    for (int s = 0; s < 3; s++)
        for (int j = 0; j < 7; j++) Vv[s][j] = Q[s + 1][j] * E[s + 1][j];

    auto pk2 = [](float a, float b) -> float {
        h2_t h;
        h[0] = (__fp16)a;
        h[1] = (__fp16)b;
        union { h2_t h; float f; } c;
        c.h = h;
        return c.f;
    };
    for (int k = 0; k < 7; k++) {
        g_c[k] = pk2(E[0][k], E[1][k]);
        g_c[7 + k] = pk2(E[2][k], E[3][k]);
        g_c[14 + k] = pk2(Vv[0][k], Vv[1][k]);
        g_c[21 + k] = pk2(Vv[2][k], Vv[2][k]);
        g_c[28 + k] = pk2(E[1][k], E[2][k]);
        g_c[35 + k] = pk2(E[2][k], -Vv[2][k]);
        g_c[42 + k] = pk2(-Vv[0][k], -Vv[1][k]);
        g_c[49 + k] = pk2(E[3][k], 0.f);
    }
    for (int s = 0; s < 3; s++) {
        float gs = 0.f;
        for (int i = 0; i < 7; i++)
            for (int j = 0; j < 7; j++) gs += E[s][i] * E[s][j];
        g_c[56 + s] = 1.0f / (gs * gs);
    }
    for (int s = 1; s < 4; s++) {
        float n = 0.f;
        for (int i = 0; i < 7; i++)
            for (int j = 0; j < 7; j++) {
                float v = E[s][i] * E[s][j] * (1.0f - Q[s][i] - Q[s][j]);
                n += fabsf(v);
            }
        g_c[59 + (s - 1)] = 1.0f / (n * n);
    }
    g_c[62] = 0.f;
    g_c[63] = 0.f;
}

__global__ __launch_bounds__(256) void sum_target_kernel(const float4* __restrict__ t4) {
    int tid = blockIdx.x * 256 + threadIdx.x;
    float s = 0.f;
    for (int i = tid; i < NPIX / 4; i += 2048 * 256) {
        float4 v = t4[i];
        s += (v.x + v.y) + (v.z + v.w);
    }
    for (int off = 32; off > 0; off >>= 1) s += __shfl_down(s, off);
    __shared__ float ps[4];
    int lane = threadIdx.x & 63, wid = threadIdx.x >> 6;
    if (lane == 0) ps[wid] = s;
    __syncthreads();
    if (threadIdx.x == 0) atomicAdd(&g_c[63], (ps[0] + ps[1]) + (ps[2] + ps[3]));
}

__global__ __launch_bounds__(256, 4) void main_kernel(const float* __restrict__ R,
                                                      const float* __restrict__ T) {
    __shared__ float sd[38][44];    // d = r-t; pixel x <-> col jj = x+4; pitch 44 (11%8=3)
    __shared__ float sr[34][40];    // r (-inf padded), rows = pixelrow+1
    __shared__ float st[34][40];    // t (-inf padded)
    __shared__ uint4 hrec[32][39];  // transposed h record {he0,he1|he2,he3|tm0,tm1|tm2,tm2}
    __shared__ float red[4];

    const int tid = threadIdx.x;
    const int gx0 = blockIdx.x * 32, gy0 = blockIdx.y * 32;
    const int z0 = blockIdx.z * ZPB;

    // packed coefficients -> SGPR uints (VOP3P takes one SGPR source)
    h2_t cE01[7], cE23[7], cV01[7], cV2[7], d2c[7], d3c[7], d4c[7], d5c[7];
#pragma unroll
    for (int k = 0; k < 7; k++) {
        cE01[k] = as_h2(rdflu(g_c[k]));
        cE23[k] = as_h2(rdflu(g_c[7 + k]));
        cV01[k] = as_h2(rdflu(g_c[14 + k]));
        cV2[k] = as_h2(rdflu(g_c[21 + k]));
        d2c[k] = as_h2(rdflu(g_c[28 + k]));
        d3c[k] = as_h2(rdflu(g_c[35 + k]));
        d4c[k] = as_h2(rdflu(g_c[42 + k]));
        d5c[k] = as_h2(rdflu(g_c[49 + k]));
    }
    float invS4[3], invN2[3];
#pragma unroll
    for (int s = 0; s < 3; s++) {
        invS4[s] = rdfl(g_c[56 + s]);
        invN2[s] = rdfl(g_c[59 + s]);
    }
    const float mean = rdfl(g_c[63]) * (1.0f / (float)NPIX);

    // ---- per-thread load geometry (z-independent) ----
    const int q0 = tid, q1 = tid + 256;
    const bool has1 = (q1 < 380);
    const int i0 = q0 / 10, c0 = q0 - 10 * i0;
    const int i1 = q1 / 10, c1 = q1 - 10 * i1;
    const int gy_0 = gy0 + i0 - 3, gxb0 = gx0 - 4 + 4 * c0;
    const int gy_1 = gy0 + i1 - 3, gxb1 = gx0 - 4 + 4 * c1;
    const int o0 = min(max(gy_0, 0), IMG - 1) * IMG + min(max(gxb0, 0), IMG - 4);
    const int o1 = min(max(gy_1, 0), IMG - 1) * IMG + min(max(gxb1, 0), IMG - 4);
    const bool vy0 = ((unsigned)gy_0 < IMG), vy1 = ((unsigned)gy_1 < IMG);
    bool m0[4], m1[4];
#pragma unroll
    for (int e = 0; e < 4; e++) {
        m0[e] = vy0 && ((unsigned)(gxb0 + e) < IMG);
        m1[e] = vy1 && ((unsigned)(gxb1 + e) < IMG);
    }

    const int x = tid & 31;
    const int y0 = (tid >> 5) * 4;

    float4 ra, ta, rb, tb;  // prefetch registers

#define LOAD_TILE(zz)                          \
    {                                          \
        const float* Rz = R + (long)(zz)*IMG2; \
        const float* Tz = T + (long)(zz)*IMG2; \
        ra = *(const float4*)(Rz + o0);        \
        ta = *(const float4*)(Tz + o0);        \
        if (has1) {                            \
            rb = *(const float4*)(Rz + o1);    \
            tb = *(const float4*)(Tz + o1);    \
        }                                      \
    }

#define WRITE_TILE()                                                                         \
    {                                                                                        \
        float rv[4] = {ra.x, ra.y, ra.z, ra.w};                                              \
        float tv[4] = {ta.x, ta.y, ta.z, ta.w};                                              \
        float dq[4], rq[4], tq[4];                                                           \
        _Pragma("unroll") for (int e = 0; e < 4; e++) {                                      \
            dq[e] = m0[e] ? (rv[e] - tv[e]) : 0.f;                                           \
            rq[e] = m0[e] ? rv[e] : -INFINITY;                                               \
            tq[e] = m0[e] ? tv[e] : -INFINITY;                                               \
        }                                                                                    \
        *(float4*)&sd[i0][4 * c0] = make_float4(dq[0], dq[1], dq[2], dq[3]);                 \
        if (i0 >= 2 && i0 < 36) {                                                            \
            *(float4*)&sr[i0 - 2][4 * c0] = make_float4(rq[0], rq[1], rq[2], rq[3]);         \
            *(float4*)&st[i0 - 2][4 * c0] = make_float4(tq[0], tq[1], tq[2], tq[3]);         \
        }                                                                                    \
        if (has1) {                                                                          \
            float rv1[4] = {rb.x, rb.y, rb.z, rb.w};                                         \
            float tv1[4] = {tb.x, tb.y, tb.z, tb.w};                                         \
            float dq1[4], rq1[4], tq1[4];                                                    \
            _Pragma("unroll") for (int e = 0; e < 4; e++) {                                  \
                dq1[e] = m1[e] ? (rv1[e] - tv1[e]) : 0.f;                                    \
                rq1[e] = m1[e] ? rv1[e] : -INFINITY;                                         \
                tq1[e] = m1[e] ? tv1[e] : -INFINITY;                                         \
            }                                                                                \
            *(float4*)&sd[i1][4 * c1] = make_float4(dq1[0], dq1[1], dq1[2], dq1[3]);         \
            if (i1 >= 2 && i1 < 36) {                                                        \
                *(float4*)&sr[i1 - 2][4 * c1] = make_float4(rq1[0], rq1[1], rq1[2], rq1[3]); \
                *(float4*)&st[i1 - 2][4 * c1] = make_float4(tq1[0], tq1[1], tq1[2], tq1[3]); \
            }                                                                                \
        }                                                                                    \
    }

    LOAD_TILE(z0);
    WRITE_TILE();
    __syncthreads();

    float total = 0.f;

    for (int it = 0; it < ZPB; ++it) {
        const bool havenext = (it + 1 < ZPB);
        if (havenext) LOAD_TILE(z0 + it + 1);  // issue early; consumed after S1

        // ---- phase 2: local terms (sobel, point, recon, maxpool), f32 ----
        {
            float dw[6][3];
#pragma unroll
            for (int r = 0; r < 6; r++)
#pragma unroll
                for (int c = 0; c < 3; c++) dw[r][c] = sd[y0 + 2 + r][x + 3 + c];
            float rx[6], rs[6];
#pragma unroll
            for (int r = 0; r < 6; r++) {
                rx[r] = dw[r][2] - dw[r][0];
                rs[r] = dw[r][0] + 2.f * dw[r][1] + dw[r][2];
            }
            float crm[6], ctm[6], tc[6];
#pragma unroll
            for (int r = 0; r < 6; r++) {
                float a = sr[y0 + r][x + 3], b = sr[y0 + r][x + 4], c = sr[y0 + r][x + 5];
                crm[r] = fmaxf(fmaxf(a, b), c);
                float a2 = st[y0 + r][x + 3], b2 = st[y0 + r][x + 4], c2 = st[y0 + r][x + 5];
                ctm[r] = fmaxf(fmaxf(a2, b2), c2);
                tc[r] = b2;
            }
#pragma unroll
            for (int yy = 0; yy < 4; yy++) {
                float sx = rx[yy] + 2.f * rx[yy + 1] + rx[yy + 2];
                float sy = rs[yy + 2] - rs[yy];
                float pt = 4.f * dw[yy + 1][1] - dw[yy][1] - dw[yy + 2][1] - dw[yy + 1][0] -
                           dw[yy + 1][2];
                float d = dw[yy + 1][1];
                float w2 = (tc[yy + 1] > mean) ? 9.f : 1.f;
                float mr = fmaxf(fmaxf(crm[yy], crm[yy + 1]), crm[yy + 2]);
                float mt = fmaxf(fmaxf(ctm[yy], ctm[yy + 1]), ctm[yy + 2]);
                total += w2 * d * d + 2.f * (sx * sx + sy * sy) + 1.5f * pt * pt +
                         2.f * fabsf(mr - mt);
            }
        }

        // ---- phase 3: horizontal pass (packed f16), job = (xq, y), y fastest ----
        for (int j = tid; j < 304; j += 256) {
            int xq = j / 38, y = j - 38 * xq;  // xq 0..7, y 0..37
            const float* rp = &sd[y][4 * xq];
            float4 A = *(const float4*)(rp);
            float4 B = *(const float4*)(rp + 4);
            float4 C = *(const float4*)(rp + 8);
            float w[12] = {A.x, A.y, A.z, A.w, B.x, B.y, B.z, B.w, C.x, C.y, C.z, C.w};
            h2_t wp[12];
#pragma unroll
            for (int i = 0; i < 12; i++) wp[i] = __builtin_amdgcn_cvt_pkrtz(w[i], w[i]);
#pragma unroll
            for (int p = 0; p < 4; p++) {
                h2_t aE01 = h2z(), aE23 = h2z(), aV01 = h2z(), aV2 = h2z();
#pragma unroll
                for (int k = 0; k < 7; k++) {
                    h2_t d = wp[p + 1 + k];
                    aE01 = cE01[k] * d + aE01;
                    aE23 = cE23[k] * d + aE23;
                    aV01 = cV01[k] * d + aV01;
                    aV2 = cV2[k] * d + aV2;
                }
                h2_t he12 = __builtin_shufflevector(aE01, aE23, 1, 2);  // (he1,he2)
                h2_t tm01 = he12 - aV01;                                // (tm0,tm1)
                h2_t he33 = __builtin_shufflevector(aE23, aE23, 1, 1);  // (he3,he3)
                h2_t tm22 = he33 - aV2;                                 // (tm2,tm2)
                hrec[4 * xq + p][y] =
                    make_uint4(as_u(aE01), as_u(aE23), as_u(tm01), as_u(tm22));
            }
        }
        __syncthreads();  // S1: sd/sr/st reads + hrec writes complete

        if (havenext) WRITE_TILE();  // stage next tile (disjoint from hrec)

        // ---- phase 4: vertical pass (packed f16), rolling over 10 h-rows ----
        {
            h2_t A1[4], A2[4], A3[4], A4[4], A5[4];
#pragma unroll
            for (int yy = 0; yy < 4; yy++) {
                A1[yy] = h2z();
                A2[yy] = h2z();
                A3[yy] = h2z();
                A4[yy] = h2z();
                A5[yy] = h2z();
            }
#pragma unroll
            for (int q = 0; q < 10; q++) {
                uint4 rec = hrec[x][y0 + q];
                h2_t rx = as_h2(rec.x), ry = as_h2(rec.y);
                h2_t rz = as_h2(rec.z), rw = as_h2(rec.w);
                h2_t r12 = __builtin_shufflevector(rx, ry, 1, 2);  // (he1,he2)
#pragma unroll
                for (int yy = 0; yy < 4; yy++) {
                    const int k = q - yy;
                    if (k >= 0 && k <= 6) {
                        A1[yy] = cE01[k] * rx + A1[yy];  // (g0, g1)
                        A2[yy] = d2c[k] * rz + A2[yy];   // (aL0a, aL1a)
                        A3[yy] = d3c[k] * ry + A3[yy];   // (g2, aL2b)
                        A4[yy] = d4c[k] * r12 + A4[yy];  // (aL0b, aL1b)
                        A5[yy] = d5c[k] * rw + A5[yy];   // (aL2a, 0)
                    }
                }
            }
#pragma unroll
            for (int yy = 0; yy < 4; yy++) {
                h2_t Bp = A2[yy] + A4[yy];  // (aL0, aL1)
                float g0 = (float)A1[yy][0], g1 = (float)A1[yy][1];
                float g2 = (float)A3[yy][0];
                float aL0 = (float)Bp[0], aL1 = (float)Bp[1];
                float aL2 = (float)A5[yy][0] + (float)A3[yy][1];
                total += invS4[0] * g0 * g0 + invS4[1] * g1 * g1 + invS4[2] * g2 * g2 +
                         invN2[0] * aL0 * aL0 + invN2[1] * aL1 * aL1 + invN2[2] * aL2 * aL2;
            }
        }
        __syncthreads();  // S2: next-tile LDS writes visible; hrec reads done
    }

    // ---- reduction ----
    for (int off = 32; off > 0; off >>= 1) total += __shfl_down(total, off);
    int lane = tid & 63, wid = tid >> 6;
    if (lane == 0) red[wid] = total;
    __syncthreads();
    if (tid == 0) atomicAdd(&g_c[62], (red[0] + red[1]) + (red[2] + red[3]));
}

__global__ void finalize_kernel(float* __restrict__ out) {
    if (threadIdx.x == 0 && blockIdx.x == 0) out[0] = g_c[62] * (1.0f / (float)NPIX);
}

extern "C" void kernel_launch(void* const* d_in, const int* in_sizes, int n_in,
                              void* d_out, int out_size, void* d_ws, size_t ws_size,
                              hipStream_t stream) {
    const float* recon = (const float*)d_in[0];
    const float* target = (const float*)d_in[1];

    hipLaunchKernelGGL(precompute_kernel, dim3(1), dim3(64), 0, stream);
    hipLaunchKernelGGL(sum_target_kernel, dim3(2048), dim3(256), 0, stream,
                       (const float4*)target);
    dim3 grid(16, 16, 64 / ZPB), block(256);
    hipLaunchKernelGGL(main_kernel, grid, block, 0, stream, recon, target);
    hipLaunchKernelGGL(finalize_kernel, dim3(1), dim3(1), 0, stream, (float*)d_out);
}